// Round 3
// baseline (444.764 us; speedup 1.0000x reference)
//
#include <hip/hip_runtime.h>

#define BN 512
#define VN 6890
#define JN 24
#define NBETA 10
#define PFD 207      // (J-1)*9
#define NCOL 20670   // V*3

#define VT 256       // vertices per skin block
#define CT 768       // columns per skin block (= threads)
#define BT 32        // batches per skin block
#define BTILES (BN / BT)                 // 16
#define VTILES ((VN + VT - 1) / VT)      // 27
#define JSL 8
#define SLICE ((VN + JSL - 1) / JSL)     // 862

// ---------------- Kernel 1: batch-independent joint constants (partials) ----
// jcp[(j*8+s)*33 + i]: partial sums over vertex slice s.
// i = c*11 + 0      -> sum_v Jr[j,v]*vt[v,c]
// i = c*11 + 1 + k  -> sum_v Jr[j,v]*sd[v,c,k]
__global__ void k_jc(const float* __restrict__ Jr, const float* __restrict__ vt,
                     const float* __restrict__ sd, float* __restrict__ jcp) {
    int j = blockIdx.x, s = blockIdx.y;
    int tid = threadIdx.x;  // 256
    int v_beg = s * SLICE, v_end = min(VN, v_beg + SLICE);
    float acc[33];
#pragma unroll
    for (int i = 0; i < 33; ++i) acc[i] = 0.f;
    for (int v = v_beg + tid; v < v_end; v += 256) {
        float w = Jr[(size_t)j * VN + v];
        const float* vtp = vt + (size_t)v * 3;
        const float* sdp = sd + (size_t)v * 30;
#pragma unroll
        for (int c = 0; c < 3; ++c) {
            acc[c * 11] += w * vtp[c];
#pragma unroll
            for (int k = 0; k < 10; ++k) acc[c * 11 + 1 + k] += w * sdp[c * 10 + k];
        }
    }
#pragma unroll
    for (int i = 0; i < 33; ++i) {
        float x = acc[i];
        for (int m = 32; m >= 1; m >>= 1) x += __shfl_xor(x, m, 64);
        acc[i] = x;
    }
    __shared__ float red[4][33];
    int wave = tid >> 6, lane = tid & 63;
    if (lane == 0) {
#pragma unroll
        for (int i = 0; i < 33; ++i) red[wave][i] = acc[i];
    }
    __syncthreads();
    if (tid < 33) jcp[(j * JSL + s) * 33 + tid] =
        red[0][tid] + red[1][tid] + red[2][tid] + red[3][tid];
}

// ---------------- Kernel 2: per-batch rodrigues + chain + A ----------------
__global__ void k_batch(const float* __restrict__ pose, const float* __restrict__ betas,
                        const int* __restrict__ parents, const float* __restrict__ jcp,
                        float* __restrict__ pf_out, float* __restrict__ A_out) {
    int b = blockIdx.x;
    int tid = threadIdx.x;  // 64
    __shared__ float rot[JN][9];
    __shared__ float Jts[JN][3];
    __shared__ float Tw[JN][12];
    __shared__ int par[JN];
    if (tid < JN) par[tid] = parents[tid];
    if (tid < JN) {
        int j = tid;
        float rx = pose[b * 72 + j * 3 + 0];
        float ry = pose[b * 72 + j * 3 + 1];
        float rz = pose[b * 72 + j * 3 + 2];
        float angle = sqrtf(rx * rx + ry * ry + rz * rz + 1e-16f);
        float inv = 1.f / angle;
        float x = rx * inv, y = ry * inv, z = rz * inv;
        float s = sinf(angle), c = cosf(angle);
        float C = 1.f - c;
        rot[j][0] = c + C * x * x;
        rot[j][1] = C * x * y - s * z;
        rot[j][2] = C * x * z + s * y;
        rot[j][3] = C * x * y + s * z;
        rot[j][4] = c + C * y * y;
        rot[j][5] = C * y * z - s * x;
        rot[j][6] = C * x * z - s * y;
        rot[j][7] = C * y * z + s * x;
        rot[j][8] = c + C * z * z;
        float jcv[33];
#pragma unroll
        for (int i = 0; i < 33; ++i) {
            float t = 0.f;
            for (int s2 = 0; s2 < JSL; ++s2) t += jcp[(j * JSL + s2) * 33 + i];
            jcv[i] = t;
        }
#pragma unroll
        for (int ci = 0; ci < 3; ++ci) {
            float t = jcv[ci * 11];
#pragma unroll
            for (int k = 0; k < 10; ++k) t += betas[b * 10 + k] * jcv[ci * 11 + 1 + k];
            Jts[j][ci] = t;
        }
    }
    __syncthreads();
    for (int idx = tid; idx < PFD; idx += 64) {
        int j = idx / 9 + 1;
        int e = idx % 9;
        float vI = (e == 0 || e == 4 || e == 8) ? 1.f : 0.f;
        pf_out[(size_t)b * PFD + idx] = rot[j][e] - vI;
    }
    if (tid < 12) {
        int r = tid >> 2, cc = tid & 3;
        Tw[0][tid] = (cc < 3) ? rot[0][r * 3 + cc] : Jts[0][r];
    }
    __syncthreads();
    for (int i = 1; i < JN; ++i) {
        if (tid < 12) {
            int p = par[i];
            int r = tid >> 2, cc = tid & 3;
            float val;
            if (cc < 3) {
                val = Tw[p][r * 4 + 0] * rot[i][0 * 3 + cc] +
                      Tw[p][r * 4 + 1] * rot[i][1 * 3 + cc] +
                      Tw[p][r * 4 + 2] * rot[i][2 * 3 + cc];
            } else {
                float t0 = Jts[i][0] - Jts[p][0];
                float t1 = Jts[i][1] - Jts[p][1];
                float t2 = Jts[i][2] - Jts[p][2];
                val = Tw[p][r * 4 + 0] * t0 + Tw[p][r * 4 + 1] * t1 +
                      Tw[p][r * 4 + 2] * t2 + Tw[p][r * 4 + 3];
            }
            Tw[i][tid] = val;
        }
        __syncthreads();
    }
    if (tid < JN) {
        int j = tid;
        float Ar[12];
#pragma unroll
        for (int r = 0; r < 3; ++r) {
#pragma unroll
            for (int cc = 0; cc < 3; ++cc) Ar[r * 4 + cc] = Tw[j][r * 4 + cc];
            Ar[r * 4 + 3] = Tw[j][r * 4 + 3] -
                            (Tw[j][r * 4 + 0] * Jts[j][0] + Tw[j][r * 4 + 1] * Jts[j][1] +
                             Tw[j][r * 4 + 2] * Jts[j][2]);
        }
#pragma unroll
        for (int e = 0; e < 12; ++e) A_out[((size_t)b * JN + j) * 12 + e] = Ar[e];
    }
}

// ---------------- Kernel 3: column-mapped fused shape + pose-GEMM + skinning
// grid (BTILES=16, VTILES=27), block 768.
// thread t owns output column (v0*3 + t) for BT=32 batches; pf/A/betas/trans
// are wave-uniform -> scalar loads; posedirs loads are stride-1 coalesced.
__global__ void __launch_bounds__(CT, 6)
k_skin2(const float* __restrict__ betas, const float* __restrict__ trans,
        const float* __restrict__ vt, const float* __restrict__ sd,
        const float* __restrict__ pd, const float* __restrict__ wts,
        const float* __restrict__ pf, const float* __restrict__ Ag,
        float* __restrict__ out) {
    const int t = threadIdx.x;
    const int b0 = blockIdx.x * BT;
    const int v0 = blockIdx.y * VT;
    const int nv = min(VT, VN - v0);
    const int nc = nv * 3;
    const bool act = (t < nc);
    const int cg = v0 * 3 + t;
    const int cgc = act ? cg : (NCOL - 1);   // clamped, always in-bounds

    __shared__ float ex[3 * CT];       // per-round exchange (3 batches)
    __shared__ float wts_s[VT][25];    // padded: stride 25 coprime with 32

    for (int i = t; i < nv * JN; i += CT) {
        int v_ = i / JN, j = i % JN;
        wts_s[v_][j] = wts[(size_t)(v0 + v_) * JN + j];
    }

    // shape init: acc[bi] = vt[c] + sum_k betas[b,k] * sd[v, c%3, k]
    float sdv[NBETA];
    {
        int vi = cgc / 3, ci = cgc % 3;
        const float* sp = sd + (size_t)vi * 30 + ci * 10;
#pragma unroll
        for (int k = 0; k < NBETA; ++k) sdv[k] = sp[k];
    }
    float vtc = vt[cgc];
    float acc[BT];
#pragma unroll
    for (int bi = 0; bi < BT; ++bi) {
        const float* bp = betas + (size_t)(b0 + bi) * NBETA;   // uniform -> s_load
        float a = vtc;
#pragma unroll
        for (int k = 0; k < NBETA; ++k) a = fmaf(bp[k], sdv[k], a);
        acc[bi] = a;
    }

    // pose GEMM: acc[bi] += sum_k pf[b,k] * pd[k, cg]
    const float* __restrict__ pcol = pd + cgc;
    const float* __restrict__ pfb = pf + (size_t)b0 * PFD;     // uniform base
#pragma unroll 3
    for (int k = 0; k < PFD; ++k) {
        float p = pcol[(size_t)k * NCOL];
#pragma unroll
        for (int bi = 0; bi < BT; ++bi)
            acc[bi] = fmaf(pfb[(size_t)bi * PFD + k], p, acc[bi]);
    }

    __syncthreads();   // wts_s ready; GEMM accs final

    const int v_loc = t & (VT - 1);
    const int jrole = t >> 8;          // 0..2: which batch of the round

    // epilogue: 3 batches per round through LDS exchange
#pragma unroll 1
    for (int r = 0; r < (BT + 2) / 3; ++r) {
        int bb = r * 3;
        if (act) {
#pragma unroll
            for (int jj = 0; jj < 3; ++jj)
                if (bb + jj < BT) ex[jj * CT + t] = acc[bb + jj];
        }
        __syncthreads();
        int bi = bb + jrole;
        if (bi < BT && v_loc < nv) {
            int b = b0 + bi;
            float x = ex[jrole * CT + 3 * v_loc + 0];
            float y = ex[jrole * CT + 3 * v_loc + 1];
            float z = ex[jrole * CT + 3 * v_loc + 2];
            const float* __restrict__ Ab = Ag + (size_t)b * (JN * 12);  // uniform -> s_load
            float T[12];
#pragma unroll
            for (int e = 0; e < 12; ++e) T[e] = 0.f;
#pragma unroll
            for (int j = 0; j < JN; ++j) {
                float wj = wts_s[v_loc][j];
#pragma unroll
                for (int e = 0; e < 12; ++e) T[e] = fmaf(wj, Ab[j * 12 + e], T[e]);
            }
            float tx = trans[b * 3 + 0], ty = trans[b * 3 + 1], tz = trans[b * 3 + 2];
            float o0 = fmaf(T[0], x, fmaf(T[1], y, fmaf(T[2],  z, T[3])))  + tx;
            float o1 = fmaf(T[4], x, fmaf(T[5], y, fmaf(T[6],  z, T[7])))  + ty;
            float o2 = fmaf(T[8], x, fmaf(T[9], y, fmaf(T[10], z, T[11]))) + tz;
            float* op = out + ((size_t)b * VN + v0 + v_loc) * 3;
            op[0] = o0; op[1] = o1; op[2] = o2;
        }
        __syncthreads();
    }
}

extern "C" void kernel_launch(void* const* d_in, const int* in_sizes, int n_in,
                              void* d_out, int out_size, void* d_ws, size_t ws_size,
                              hipStream_t stream) {
    const float* pose       = (const float*)d_in[0];
    const float* betas      = (const float*)d_in[1];
    const float* trans      = (const float*)d_in[2];
    const float* v_template = (const float*)d_in[3];
    const float* shapedirs  = (const float*)d_in[4];
    const float* posedirs   = (const float*)d_in[5];
    const float* Jreg       = (const float*)d_in[6];
    const float* weights    = (const float*)d_in[7];
    const int*   parents    = (const int*)d_in[8];
    float* out = (float*)d_out;
    float* ws  = (float*)d_ws;

    float* jcp = ws;                       // 24*8*33 = 6336 floats
    float* pfw = ws + 8192;                // 512*207 = 105984
    float* Aw  = ws + 8192 + 105984;       // 512*288 = 147456

    hipLaunchKernelGGL(k_jc, dim3(JN, JSL), dim3(256), 0, stream,
                       Jreg, v_template, shapedirs, jcp);
    hipLaunchKernelGGL(k_batch, dim3(BN), dim3(64), 0, stream,
                       pose, betas, parents, jcp, pfw, Aw);
    hipLaunchKernelGGL(k_skin2, dim3(BTILES, VTILES), dim3(CT), 0, stream,
                       betas, trans, v_template, shapedirs, posedirs, weights,
                       pfw, Aw, out);
}

// Round 5
// 146.048 us; speedup vs baseline: 3.0453x; 3.0453x over previous
//
#include <hip/hip_runtime.h>

typedef float f32x4 __attribute__((ext_vector_type(4)));
typedef short s16x8 __attribute__((ext_vector_type(8)));

#define BN 512
#define VN 6890
#define JN 24
#define NBETA 10
#define PFD 207      // (J-1)*9
#define NCOL 20670   // V*3
#define KP 224       // padded K: 207 pose + 10 betas + 1 template + 6 zero
#define NKT 7        // K tiles of 32
#define NVT 431      // vertex tiles of 16 (ceil 6890/16)
#define NVTP 432
#define JSL 8
#define SLICE ((VN + JSL - 1) / JSL)

__device__ __forceinline__ unsigned short f2bf(float f) {
    union { float f; unsigned int u; } v; v.f = f;
    unsigned int u = v.u;
    return (unsigned short)((u + 0x7FFFu + ((u >> 16) & 1u)) >> 16);  // RNE
}

// ---------------- Kernel 1: joint-regressor constants (partial sums) --------
__global__ void k_jc(const float* __restrict__ Jr, const float* __restrict__ vt,
                     const float* __restrict__ sd, float* __restrict__ jcp) {
    int j = blockIdx.x, s = blockIdx.y;
    int tid = threadIdx.x;  // 256
    int v_beg = s * SLICE, v_end = min(VN, v_beg + SLICE);
    float acc[33];
#pragma unroll
    for (int i = 0; i < 33; ++i) acc[i] = 0.f;
    for (int v = v_beg + tid; v < v_end; v += 256) {
        float w = Jr[(size_t)j * VN + v];
        const float* vtp = vt + (size_t)v * 3;
        const float* sdp = sd + (size_t)v * 30;
#pragma unroll
        for (int c = 0; c < 3; ++c) {
            acc[c * 11] += w * vtp[c];
#pragma unroll
            for (int k = 0; k < 10; ++k) acc[c * 11 + 1 + k] += w * sdp[c * 10 + k];
        }
    }
#pragma unroll
    for (int i = 0; i < 33; ++i) {
        float x = acc[i];
        for (int m = 32; m >= 1; m >>= 1) x += __shfl_xor(x, m, 64);
        acc[i] = x;
    }
    __shared__ float red[4][33];
    int wave = tid >> 6, lane = tid & 63;
    if (lane == 0) {
#pragma unroll
        for (int i = 0; i < 33; ++i) red[wave][i] = acc[i];
    }
    __syncthreads();
    if (tid < 33) jcp[(j * JSL + s) * 33 + tid] =
        red[0][tid] + red[1][tid] + red[2][tid] + red[3][tid];
}

// ---------------- Kernel 2: weights -> B-fragment layout (bf16) -------------
// wfrag[vt][l*8+i] = weights[v = vt*16 + (l&15)][j = (l>>4)*8 + i], 0-padded.
__global__ void k_wf(const float* __restrict__ wts, unsigned short* __restrict__ wfrag) {
    int vt = blockIdx.x, l = threadIdx.x;  // 64
    int v = vt * 16 + (l & 15), j0 = (l >> 4) * 8;
    s16x8 o;
#pragma unroll
    for (int i = 0; i < 8; ++i) {
        int j = j0 + i;
        float val = (v < VN && j < JN) ? wts[(size_t)v * JN + j] : 0.f;
        o[i] = (short)f2bf(val);
    }
    *(s16x8*)(wfrag + ((size_t)vt * 512 + l * 8)) = o;
}

// ---------------- Kernel 3: posedirs+shapedirs+v_template -> B-frags --------
// pdb_frag[c][kt][vt][l*8+i] = Bext[c][k = kt*32+(l>>4)*8+i][v = vt*16+(l&15)]
// where Bext rows: k<207 posedirs, 207..216 shapedirs, 217 v_template, else 0.
__global__ void __launch_bounds__(256) k_cvt(const float* __restrict__ pd,
                                             const float* __restrict__ sd,
                                             const float* __restrict__ vtm,
                                             unsigned short* __restrict__ pdb_frag) {
    int kt = blockIdx.x, vg = blockIdx.y, tid = threadIdx.x;
    int v0 = vg * 32;
    __shared__ float lds[32][96];
    for (int idx = tid; idx < 32 * 96; idx += 256) {
        int kk = idx / 96, cc = idx % 96;
        int k = kt * 32 + kk;
        int col = v0 * 3 + cc;
        float val = 0.f;
        if (col < NCOL) {
            if (k < PFD) val = pd[(size_t)k * NCOL + col];
            else if (k < 217) { int v = col / 3, c = col % 3; val = sd[(size_t)v * 30 + c * 10 + (k - PFD)]; }
            else if (k == 217) val = vtm[col];
        }
        lds[kk][cc] = val;
    }
    __syncthreads();
    int l = tid & 63;
    for (int f = tid >> 6; f < 6; f += 4) {
        int c = f >> 1, vloc = f & 1;
        int kl = (l >> 4) * 8, vl = (l & 15) + vloc * 16;
        s16x8 o;
#pragma unroll
        for (int i = 0; i < 8; ++i) o[i] = (short)f2bf(lds[kl + i][vl * 3 + c]);
        *(s16x8*)(pdb_frag + (((size_t)(c * NKT + kt) * NVTP + (vg * 2 + vloc)) * 512 + l * 8)) = o;
    }
}

// ---------------- Kernel 4: per-batch rodrigues + chain + frag writers ------
// pf_frag[g][kt][l*8+i] = pf_ext[b = g*16+(l&15)][k = kt*32+(l>>4)*8+i]
//   pf_ext: 0..206 pose feature, 207..216 betas, 217 = 1.0, rest 0.
// Ab_frag[b][l*8+i] = A_ext[b][j=(l>>4)*8+i][e=l&15]  (e=m*4+n, trans folded), 0-pad.
__global__ void k_batch(const float* __restrict__ pose, const float* __restrict__ betas,
                        const float* __restrict__ trans, const int* __restrict__ parents,
                        const float* __restrict__ jcp,
                        unsigned short* __restrict__ pf_frag,
                        unsigned short* __restrict__ Ab_frag) {
    int b = blockIdx.x;
    int tid = threadIdx.x;  // 64
    __shared__ float rot[JN][9];
    __shared__ float Jts[JN][3];
    __shared__ float Tw[JN][12];
    __shared__ float pf_s[KP];
    __shared__ float A_s[JN][12];
    __shared__ int par[JN];
    if (tid < JN) par[tid] = parents[tid];
    if (tid < JN) {
        int j = tid;
        float rx = pose[b * 72 + j * 3 + 0];
        float ry = pose[b * 72 + j * 3 + 1];
        float rz = pose[b * 72 + j * 3 + 2];
        float angle = sqrtf(rx * rx + ry * ry + rz * rz + 1e-16f);
        float inv = 1.f / angle;
        float x = rx * inv, y = ry * inv, z = rz * inv;
        float s = sinf(angle), c = cosf(angle);
        float C = 1.f - c;
        rot[j][0] = c + C * x * x;
        rot[j][1] = C * x * y - s * z;
        rot[j][2] = C * x * z + s * y;
        rot[j][3] = C * x * y + s * z;
        rot[j][4] = c + C * y * y;
        rot[j][5] = C * y * z - s * x;
        rot[j][6] = C * x * z - s * y;
        rot[j][7] = C * y * z + s * x;
        rot[j][8] = c + C * z * z;
        float jcv[33];
#pragma unroll
        for (int i = 0; i < 33; ++i) {
            float t = 0.f;
            for (int s2 = 0; s2 < JSL; ++s2) t += jcp[(j * JSL + s2) * 33 + i];
            jcv[i] = t;
        }
#pragma unroll
        for (int ci = 0; ci < 3; ++ci) {
            float t = jcv[ci * 11];
#pragma unroll
            for (int k = 0; k < 10; ++k) t += betas[b * 10 + k] * jcv[ci * 11 + 1 + k];
            Jts[j][ci] = t;
        }
    }
    __syncthreads();
    for (int idx = tid; idx < KP; idx += 64) {
        float val;
        if (idx < PFD) {
            int j = idx / 9 + 1, e = idx % 9;
            val = rot[j][e] - ((e == 0 || e == 4 || e == 8) ? 1.f : 0.f);
        } else if (idx < 217) val = betas[b * NBETA + (idx - PFD)];
        else if (idx == 217) val = 1.f;
        else val = 0.f;
        pf_s[idx] = val;
    }
    if (tid < 12) {
        int r = tid >> 2, cc = tid & 3;
        Tw[0][tid] = (cc < 3) ? rot[0][r * 3 + cc] : Jts[0][r];
    }
    __syncthreads();
    for (int i = 1; i < JN; ++i) {
        if (tid < 12) {
            int p = par[i];
            int r = tid >> 2, cc = tid & 3;
            float val;
            if (cc < 3) {
                val = Tw[p][r * 4 + 0] * rot[i][0 * 3 + cc] +
                      Tw[p][r * 4 + 1] * rot[i][1 * 3 + cc] +
                      Tw[p][r * 4 + 2] * rot[i][2 * 3 + cc];
            } else {
                float t0 = Jts[i][0] - Jts[p][0];
                float t1 = Jts[i][1] - Jts[p][1];
                float t2 = Jts[i][2] - Jts[p][2];
                val = Tw[p][r * 4 + 0] * t0 + Tw[p][r * 4 + 1] * t1 +
                      Tw[p][r * 4 + 2] * t2 + Tw[p][r * 4 + 3];
            }
            Tw[i][tid] = val;
        }
        __syncthreads();
    }
    if (tid < JN) {
        int j = tid;
#pragma unroll
        for (int m = 0; m < 3; ++m) {
#pragma unroll
            for (int n = 0; n < 3; ++n) A_s[j][m * 4 + n] = Tw[j][m * 4 + n];
            A_s[j][m * 4 + 3] = Tw[j][m * 4 + 3] -
                (Tw[j][m * 4 + 0] * Jts[j][0] + Tw[j][m * 4 + 1] * Jts[j][1] +
                 Tw[j][m * 4 + 2] * Jts[j][2]) + trans[b * 3 + m];
        }
    }
    __syncthreads();
    if (tid < 28) {
        int kt = tid >> 2, hi = tid & 3;
        s16x8 o;
#pragma unroll
        for (int i = 0; i < 8; ++i) o[i] = (short)f2bf(pf_s[kt * 32 + hi * 8 + i]);
        *(s16x8*)(pf_frag + ((((b >> 4) * NKT + kt) * 512) + (hi * 16 + (b & 15)) * 8)) = o;
    }
    {
        int l = tid, e = l & 15, j0 = (l >> 4) * 8;
        s16x8 o;
#pragma unroll
        for (int i = 0; i < 8; ++i) {
            int j = j0 + i;
            o[i] = (e < 12 && j < JN) ? (short)f2bf(A_s[j][e]) : (short)0;
        }
        *(s16x8*)(Ab_frag + ((size_t)b * 512 + l * 8)) = o;
    }
}

// ---------------- Kernel 5: fused MFMA pose-GEMM + MFMA skinning ------------
// grid (8 b-tiles, 108 v-tile-quads), block 256 = 4 waves; wave = one 16-v tile,
// all 64 batches of its b-tile. No LDS, no barriers.
__global__ void __launch_bounds__(256, 4)
k_main(const unsigned short* __restrict__ pf_frag,
       const unsigned short* __restrict__ Ab_frag,
       const unsigned short* __restrict__ wfrag,
       const unsigned short* __restrict__ pdb_frag,
       float* __restrict__ out) {
    int t = threadIdx.x, l = t & 63, w = t >> 6;
    int bt = blockIdx.x;
    int vtile = blockIdx.y * 4 + w;
    if (vtile >= NVT) return;
    int b0 = bt * 64;

    s16x8 wf = *(const s16x8*)(wfrag + ((size_t)vtile * 512 + l * 8));

    f32x4 acc[3][4];
#pragma unroll
    for (int c = 0; c < 3; ++c)
#pragma unroll
        for (int bs = 0; bs < 4; ++bs) acc[c][bs] = (f32x4){0.f, 0.f, 0.f, 0.f};

    // pose+shape GEMM: vp[c][b][v] over K=224
#pragma unroll
    for (int kt = 0; kt < NKT; ++kt) {
        s16x8 af[4], bfr[3];
#pragma unroll
        for (int bs = 0; bs < 4; ++bs)
            af[bs] = *(const s16x8*)(pf_frag + ((((bt * 4 + bs) * NKT + kt) * 512) + l * 8));
#pragma unroll
        for (int c = 0; c < 3; ++c)
            bfr[c] = *(const s16x8*)(pdb_frag + (((size_t)(c * NKT + kt) * NVTP + vtile) * 512 + l * 8));
#pragma unroll
        for (int c = 0; c < 3; ++c)
#pragma unroll
            for (int bs = 0; bs < 4; ++bs)
                acc[c][bs] = __builtin_amdgcn_mfma_f32_16x16x32_bf16(af[bs], bfr[c], acc[c][bs], 0, 0, 0);
    }

    // blend: per b, T^T[e][v] = A_ext[b] (e x j) @ weights^T (j x v), then apply
    int vglob = vtile * 16 + (l & 15);
    int m = l >> 4;
    bool vok = (vglob < VN) && (m < 3);
    const f32x4 z4 = {0.f, 0.f, 0.f, 0.f};
#pragma unroll
    for (int bs = 0; bs < 4; ++bs) {
#pragma unroll
        for (int bl = 0; bl < 16; ++bl) {
            int b = bs * 16 + bl;
            s16x8 ab = *(const s16x8*)(Ab_frag + ((size_t)(b0 + b) * 512 + l * 8));
            f32x4 T = __builtin_amdgcn_mfma_f32_16x16x32_bf16(ab, wf, z4, 0, 0, 0);
            int src = ((bl >> 2) << 4) + (l & 15);
            float x = __shfl(acc[0][bs][bl & 3], src, 64);
            float y = __shfl(acc[1][bs][bl & 3], src, 64);
            float zz = __shfl(acc[2][bs][bl & 3], src, 64);
            float val = fmaf(T[0], x, fmaf(T[1], y, fmaf(T[2], zz, T[3])));
            if (vok) out[((size_t)(b0 + b) * VN + vglob) * 3 + m] = val;
        }
    }
}

extern "C" void kernel_launch(void* const* d_in, const int* in_sizes, int n_in,
                              void* d_out, int out_size, void* d_ws, size_t ws_size,
                              hipStream_t stream) {
    const float* pose       = (const float*)d_in[0];
    const float* betas      = (const float*)d_in[1];
    const float* trans      = (const float*)d_in[2];
    const float* v_template = (const float*)d_in[3];
    const float* shapedirs  = (const float*)d_in[4];
    const float* posedirs   = (const float*)d_in[5];
    const float* Jreg       = (const float*)d_in[6];
    const float* weights    = (const float*)d_in[7];
    const int*   parents    = (const int*)d_in[8];
    float* out = (float*)d_out;
    char* base = (char*)d_ws;

    float*          jcp      = (float*)(base);                    // 25 KB
    unsigned short* pf_frag  = (unsigned short*)(base + 65536);   // 224 KB
    unsigned short* Ab_frag  = (unsigned short*)(base + 393216);  // 512 KB
    unsigned short* wfrag    = (unsigned short*)(base + 917504);  // 432 KB
    unsigned short* pdb_frag = (unsigned short*)(base + 1441792); // 9.1 MB

    hipLaunchKernelGGL(k_jc, dim3(JN, JSL), dim3(256), 0, stream,
                       Jreg, v_template, shapedirs, jcp);
    hipLaunchKernelGGL(k_wf, dim3(NVTP), dim3(64), 0, stream, weights, wfrag);
    hipLaunchKernelGGL(k_cvt, dim3(NKT, 216), dim3(256), 0, stream,
                       posedirs, shapedirs, v_template, pdb_frag);
    hipLaunchKernelGGL(k_batch, dim3(BN), dim3(64), 0, stream,
                       pose, betas, trans, parents, jcp, pf_frag, Ab_frag);
    hipLaunchKernelGGL(k_main, dim3(8, 108), dim3(256), 0, stream,
                       pf_frag, Ab_frag, wfrag, pdb_frag, out);
}